// Round 4
// baseline (1187.929 us; speedup 1.0000x reference)
//
#include <hip/hip_runtime.h>

// DecoderRNN v4: 3-layer GRU, B=32768, H=100, 21 steps, VOCAB=20.
// Block = 8 waves x 128 batch rows (1 block/CU). Waves 0..6 own 16-neuron
// output tiles; wave 7 computes logits (1 step behind) during gru0.
// v4 vs v3: amdgpu_waves_per_eu(2,2) -> 256 VGPR budget so per-phase weights
// (22 frag8) stay in registers; 3 barriers/phase (was 8) via double-quad
// prefetch of the recurrent-state fragments; combined r/z tail MFMA
// (ih-tail+bias | hh-tail+bias in one 16x16x32 via per-lane address select).

#define NTHR 512
#define NBLK 256
#define ROWS_PB 128

// wp (u16) offsets (identical to v3)
#define OFF_PROJ 0                 // [112][128]
#define OFF_IH0  14336             // each [336][128]: row g*112+nn, col 100 = bias
#define OFF_HH0  57344
#define OFF_IH1  100352
#define OFF_HH1  143360
#define OFF_IH2  186368
#define OFF_HH2  229376
#define OFF_OUT  272384            // [32][128], col 100 = b_out
#define Z16_OFF  275456            // 16 B of zeros
#define WP_TOTAL 276480

// LDS (u16): 4 buffers [128][128] swizzled + 8-u16 zero pad
#define X0_OFF   0
#define H0_OFF   16384
#define H1_OFF   32768
#define H2_OFF   49152
#define ZPAD_OFF 65536
#define SMEM_U16 65544
#define SMEM_BYTES (SMEM_U16 * 2)  // 131088

using frag8 = __attribute__((ext_vector_type(8))) short;
using frag4 = __attribute__((ext_vector_type(4))) short;
using f32x4 = __attribute__((ext_vector_type(4))) float;

struct G3 { frag8 a, b, c; };

__device__ __forceinline__ unsigned short f2b(float f) {
    union { float f; unsigned u; } v; v.f = f;
    unsigned r = v.u + 0x7FFF + ((v.u >> 16) & 1);   // RNE
    return (unsigned short)(r >> 16);
}
__device__ __forceinline__ float b2f(unsigned short b) {
    union { unsigned u; float f; } v; v.u = ((unsigned)b) << 16; return v.f;
}
__device__ __forceinline__ float sigm(float x) { return 1.f / (1.f + __expf(-x)); }
__device__ __forceinline__ float tanh_fast(float x) { return 2.f / (1.f + __expf(-2.f * x)) - 1.f; }

__device__ __forceinline__ f32x4 mfma32(frag8 a, frag8 b, f32x4 c) {
    return __builtin_amdgcn_mfma_f32_16x16x32_bf16(a, b, c, 0, 0, 0);
}
__device__ __forceinline__ f32x4 dot3(const G3& w, const G3& s, f32x4 acc) {
    acc = mfma32(w.a, s.a, acc);
    acc = mfma32(w.b, s.b, acc);
    return mfma32(w.c, s.c, acc);
}

// ---------------- weight prep: f32 -> bf16, padded, bias in col 100 ----------------
__global__ void prep_kernel(const float* __restrict__ w_proj,
    const float* __restrict__ wih0, const float* __restrict__ bih0,
    const float* __restrict__ whh0, const float* __restrict__ bhh0,
    const float* __restrict__ wih1, const float* __restrict__ bih1,
    const float* __restrict__ whh1, const float* __restrict__ bhh1,
    const float* __restrict__ wih2, const float* __restrict__ bih2,
    const float* __restrict__ whh2, const float* __restrict__ bhh2,
    const float* __restrict__ w_out, const float* __restrict__ b_out,
    unsigned short* __restrict__ dst)
{
    int idx = blockIdx.x * 256 + threadIdx.x;
    if (idx >= WP_TOTAL) return;
    float v = 0.f;
    if (idx < OFF_IH0) {
        int n = idx >> 7, k = idx & 127;
        if (n < 100) v = w_proj[n * 128 + k];
    } else if (idx < OFF_OUT) {
        int r = idx - OFF_IH0;
        int mi = r / 43008;
        int e  = r - mi * 43008;
        int n = e >> 7, k = e & 127;
        int g = n / 112, nn = n - g * 112;
        if (nn < 100) {
            const float* W; const float* Bv;
            switch (mi) {
                case 0: W = wih0; Bv = bih0; break;
                case 1: W = whh0; Bv = bhh0; break;
                case 2: W = wih1; Bv = bih1; break;
                case 3: W = whh1; Bv = bhh1; break;
                case 4: W = wih2; Bv = bih2; break;
                default: W = whh2; Bv = bhh2; break;
            }
            if (k < 100) v = W[(g * 100 + nn) * 100 + k];
            else if (k == 100) v = Bv[g * 100 + nn];
        }
    } else {
        int e = idx - OFF_OUT;
        int n = e >> 7, k = e & 127;
        if (n < 20) {
            if (k < 100) v = w_out[n * 100 + k];
            else if (k == 100) v = b_out[n];
        }
    }
    dst[idx] = f2b(v);
}

// ---------------- LDS helpers (swizzled) ----------------
// logical u16 col cu of buffer-row r stored at chunk (cu>>3) ^ (r&7)
__device__ __forceinline__ int hsw(int buf, int grp, int r, int cu) {
    return buf + (grp * 16 + r) * 128 + ((((cu >> 3) ^ (r & 7)) << 3) | (cu & 7));
}
__device__ __forceinline__ G3 ldS3(const unsigned short* sm, int buf, int grp, int c16, int g4) {
    const unsigned short* p = sm + buf + (grp * 16 + c16) * 128;
    int x = c16 & 7;
    G3 s;
    s.a = *(const frag8*)(p + ((g4 ^ x) << 3));
    s.b = *(const frag8*)(p + (((4 + g4) ^ x) << 3));
    s.c = *(const frag8*)(p + (((8 + g4) ^ x) << 3));
    return s;
}
// u16 offset of the k=96..103 tail chunk of row (grp,c16) in buffer buf
__device__ __forceinline__ int tailoff(int buf, int grp, int c16) {
    return buf + (grp * 16 + c16) * 128 + ((12 ^ (c16 & 7)) << 3);
}
__device__ __forceinline__ frag8 ldsf8(const unsigned short* sm, int off) {
    return *(const frag8*)(sm + off);
}

// ---------------- weight loaders ----------------
__device__ __forceinline__ G3 ldW(const unsigned short* __restrict__ mat, int g, int ro, int g4) {
    const unsigned short* p = mat + (size_t)(g * 112 + ro) * 128 + g4 * 8;
    G3 w; w.a = *(const frag8*)p; w.b = *(const frag8*)(p + 32); w.c = *(const frag8*)(p + 64);
    return w;
}

__device__ __forceinline__ void logits_one(const unsigned short* sm,
        const G3& O0, const G3& O1, frag8 T0, frag8 T1,
        int grp, int lt, float* __restrict__ out, int rbase, int c16, int g4) {
    G3 L = ldS3(sm, H2_OFF, grp, c16, g4);
    frag8 LT = ldsf8(sm, (g4 == 0) ? tailoff(H2_OFF, grp, c16) : ZPAD_OFF);
    f32x4 a0 = {0.f, 0.f, 0.f, 0.f}, a1 = a0;
    a0 = dot3(O0, L, a0); a0 = mfma32(T0, LT, a0);
    a1 = dot3(O1, L, a1); a1 = mfma32(T1, LT, a1);
    float* po = out + (size_t)(rbase + grp * 16 + c16) * 420 + lt * 20;
    *(f32x4*)(po + g4 * 4) = a0;           // vocab 4*g4 .. +4
    if (g4 == 0) *(f32x4*)(po + 16) = a1;  // vocab 16..19
}

// ---------------- one GRU layer phase (3 barriers) ----------------
template<bool L0>
__device__ __forceinline__ void gru_phase(unsigned short* sm, int HS, int HD,
    const unsigned short* __restrict__ wih, const unsigned short* __restrict__ whh,
    const unsigned short* __restrict__ z16,
    const G3* O, const frag8* OT, int lt, float* __restrict__ out, int rbase,
    bool owner, bool vald, int c16, int g4, int ro, int nbase)
{
    G3 Wi[3], Wh[3];
    frag8 Wc0, Wc1, Tin, Thn;
    if (owner) {
#pragma unroll
        for (int g = 0; g < 3; ++g) { Wi[g] = ldW(wih, g, ro, g4); Wh[g] = ldW(whh, g, ro, g4); }
        Wc0 = *(const frag8*)(g4 == 0 ? wih + (size_t)ro * 128 + 96
                            : g4 == 1 ? whh + (size_t)ro * 128 + 96 : z16);
        Wc1 = *(const frag8*)(g4 == 0 ? wih + (size_t)(112 + ro) * 128 + 96
                            : g4 == 1 ? whh + (size_t)(112 + ro) * 128 + 96 : z16);
        Tin = *(const frag8*)(g4 == 0 ? wih + (size_t)(224 + ro) * 128 + 96 : z16);
        Thn = *(const frag8*)(g4 == 0 ? whh + (size_t)(224 + ro) * 128 + 96 : z16);
    }
    __syncthreads();                               // B0: prev-phase writes visible
    G3 D[4]; frag8 TBc[4], TBh[4];
    if (owner) {
#pragma unroll
        for (int q = 0; q < 4; ++q) {              // prefetch quad 0 (reads HD[0..3])
            D[q]   = ldS3(sm, HD, q, c16, g4);
            TBc[q] = ldsf8(sm, g4 == 0 ? tailoff(HS, q, c16)
                             : g4 == 1 ? tailoff(HD, q, c16) : ZPAD_OFF);
            TBh[q] = ldsf8(sm, g4 == 0 ? tailoff(HD, q, c16) : ZPAD_OFF);
        }
    }
    __syncthreads();                               // B1: quad-0 reads done
#pragma unroll
    for (int half = 0; half < 2; ++half) {
        if (owner) {
#pragma unroll
            for (int q = 0; q < 4; ++q) {
                const int g = half * 4 + q;
                G3 S = ldS3(sm, HS, g, c16, g4);
                frag8 TSi = ldsf8(sm, g4 == 0 ? tailoff(HS, g, c16) : ZPAD_OFF);
                f32x4 ar = {0.f, 0.f, 0.f, 0.f}, az = ar, anx = ar, anh = ar;
                ar  = dot3(Wi[0], S, ar);   ar  = dot3(Wh[0], D[q], ar);
                ar  = mfma32(Wc0, TBc[q], ar);
                az  = dot3(Wi[1], S, az);   az  = dot3(Wh[1], D[q], az);
                az  = mfma32(Wc1, TBc[q], az);
                anx = dot3(Wi[2], S, anx);  anx = mfma32(Tin, TSi, anx);
                anh = dot3(Wh[2], D[q], anh); anh = mfma32(Thn, TBh[q], anh);
                if (half == 0) {                   // prefetch quad 1 (reads HD[4..7], disjoint)
                    D[q]   = ldS3(sm, HD, 4 + q, c16, g4);
                    TBc[q] = ldsf8(sm, g4 == 0 ? tailoff(HS, 4 + q, c16)
                                     : g4 == 1 ? tailoff(HD, 4 + q, c16) : ZPAD_OFF);
                    TBh[q] = ldsf8(sm, g4 == 0 ? tailoff(HD, 4 + q, c16) : ZPAD_OFF);
                }
                int wo = hsw(HD, g, c16, nbase);
                frag4 hold = {0, 0, 0, 0};
                if (vald) hold = *(const frag4*)(sm + wo);
                frag4 hn;
#pragma unroll
                for (int j = 0; j < 4; ++j) {
                    float r  = sigm(ar[j]);
                    float z  = sigm(az[j]);
                    float nn = tanh_fast(anx[j] + r * anh[j]);
                    float ho = b2f((unsigned short)hold[j]);
                    hn[j] = (short)f2b(nn + z * (ho - nn));
                }
                if (vald) *(frag4*)(sm + wo) = hn;
            }
        } else if (L0 && lt >= 0) {
#pragma unroll
            for (int q = 0; q < 4; ++q)
                logits_one(sm, O[0], O[1], OT[0], OT[1], half * 4 + q, lt, out, rbase, c16, g4);
        }
        if (half == 0) __syncthreads();            // B2: quad-1 reads done
    }
}

// ---------------- main kernel ----------------
__attribute__((amdgpu_waves_per_eu(2, 2)))
__global__ void __launch_bounds__(NTHR) rnn_kernel(
    const float* __restrict__ enc,
    const float* __restrict__ b_proj,
    const unsigned short* __restrict__ wp,
    float* __restrict__ out)
{
    extern __shared__ unsigned short sm[];
    const int tid  = threadIdx.x;
    const int lane = tid & 63;
    const int wid  = tid >> 6;
    const int c16  = lane & 15;
    const int g4   = lane >> 4;
    const int rbase = blockIdx.x * ROWS_PB;
    const bool owner = (wid < 7);
    const int tw    = owner ? wid : 0;
    const int ro    = tw * 16 + c16;
    const int nbase = tw * 16 + g4 * 4;
    const bool vald = owner && (nbase < 100);
    const unsigned short* z16 = wp + Z16_OFF;

    // ---- init LDS: zeros, logical col 100 = 1.0 (bias), ZPAD = 0 ----
    for (int i = tid; i < SMEM_U16; i += NTHR) {
        unsigned short v = 0;
        if (i < ZPAD_OFF) {
            int r  = (i >> 7) & 127;
            int cu = i & 127;
            int lcol = ((((cu >> 3) ^ (r & 7)) << 3) | (cu & 7));
            if (lcol == 100) v = 0x3F80;
        }
        sm[i] = v;
    }

    // ---- wave 7: persistent w_out fragments ----
    G3 O[2]; frag8 OT[2];
    if (!owner) {
        const unsigned short* wout = wp + OFF_OUT;
#pragma unroll
        for (int tt = 0; tt < 2; ++tt) {
            const unsigned short* p = wout + (size_t)(tt * 16 + c16) * 128 + g4 * 8;
            O[tt].a = *(const frag8*)p; O[tt].b = *(const frag8*)(p + 32); O[tt].c = *(const frag8*)(p + 64);
            OT[tt] = *(const frag8*)((g4 == 0) ? (wout + (size_t)(tt * 16 + c16) * 128 + 96) : z16);
        }
    }
    __syncthreads();

    // ---- prologue: x0 = enc @ w_proj^T + b_proj -> X0 buffer (K=128 exact) ----
    if (owner) {
        const unsigned short* pr = wp + OFF_PROJ + (size_t)ro * 128 + g4 * 8;
        frag8 P0 = *(const frag8*)pr,        P1 = *(const frag8*)(pr + 32);
        frag8 P2 = *(const frag8*)(pr + 64), P3 = *(const frag8*)(pr + 96);
        f32x4 bp = {0.f, 0.f, 0.f, 0.f};
        if (vald) bp = *(const f32x4*)(b_proj + nbase);
#pragma unroll 1
        for (int grp = 0; grp < 8; ++grp) {
            const float* ep = enc + (size_t)(rbase + grp * 16 + c16) * 128 + g4 * 8;
            frag8 E[4];
#pragma unroll
            for (int kb = 0; kb < 4; ++kb) {
                f32x4 u = *(const f32x4*)(ep + kb * 32);
                f32x4 v = *(const f32x4*)(ep + kb * 32 + 4);
                frag8 e;
#pragma unroll
                for (int j = 0; j < 4; ++j) { e[j] = (short)f2b(u[j]); e[4 + j] = (short)f2b(v[j]); }
                E[kb] = e;
            }
            f32x4 acc = bp;
            acc = mfma32(P0, E[0], acc); acc = mfma32(P1, E[1], acc);
            acc = mfma32(P2, E[2], acc); acc = mfma32(P3, E[3], acc);
            if (vald) {
                frag4 xv;
#pragma unroll
                for (int j = 0; j < 4; ++j) xv[j] = (short)f2b(acc[j]);
                *(frag4*)(sm + hsw(X0_OFF, grp, c16, nbase)) = xv;
            }
        }
    }
    // (B0 of the first phase provides the needed sync)

    // ---- time loop: three phases; wave 7 logits(t-1) during gru0 ----
#pragma unroll 1
    for (int t = 0; t < 21; ++t) {
        gru_phase<true >(sm, X0_OFF, H0_OFF, wp + OFF_IH0, wp + OFF_HH0, z16,
                         O, OT, t - 1, out, rbase, owner, vald, c16, g4, ro, nbase);
        gru_phase<false>(sm, H0_OFF, H1_OFF, wp + OFF_IH1, wp + OFF_HH1, z16,
                         O, OT, -1, out, rbase, owner, vald, c16, g4, ro, nbase);
        gru_phase<false>(sm, H1_OFF, H2_OFF, wp + OFF_IH2, wp + OFF_HH2, z16,
                         O, OT, -1, out, rbase, owner, vald, c16, g4, ro, nbase);
    }

    // ---- tail: logits for t=20 (wave 7) ----
    __syncthreads();
    if (!owner) {
#pragma unroll 1
        for (int grp = 0; grp < 8; ++grp)
            logits_one(sm, O[0], O[1], OT[0], OT[1], grp, 20, out, rbase, c16, g4);
    }
}

extern "C" void kernel_launch(void* const* d_in, const int* in_sizes, int n_in,
                              void* d_out, int out_size, void* d_ws, size_t ws_size,
                              hipStream_t stream) {
    const float* enc    = (const float*)d_in[0];
    const float* w_proj = (const float*)d_in[1];
    const float* b_proj = (const float*)d_in[2];
    const float* wih0   = (const float*)d_in[3];
    const float* whh0   = (const float*)d_in[4];
    const float* bih0   = (const float*)d_in[5];
    const float* bhh0   = (const float*)d_in[6];
    const float* wih1   = (const float*)d_in[7];
    const float* whh1   = (const float*)d_in[8];
    const float* bih1   = (const float*)d_in[9];
    const float* bhh1   = (const float*)d_in[10];
    const float* wih2   = (const float*)d_in[11];
    const float* whh2   = (const float*)d_in[12];
    const float* bih2   = (const float*)d_in[13];
    const float* bhh2   = (const float*)d_in[14];
    const float* w_out  = (const float*)d_in[15];
    const float* b_out  = (const float*)d_in[16];
    unsigned short* wpd = (unsigned short*)d_ws;   // 552,960 B used
    float* out          = (float*)d_out;

    prep_kernel<<<(WP_TOTAL + 255) / 256, 256, 0, stream>>>(
        w_proj, wih0, bih0, whh0, bhh0, wih1, bih1, whh1, bhh1,
        wih2, bih2, whh2, bhh2, w_out, b_out, wpd);

    (void)hipFuncSetAttribute((const void*)rnn_kernel,
                              hipFuncAttributeMaxDynamicSharedMemorySize, SMEM_BYTES);
    rnn_kernel<<<NBLK, NTHR, SMEM_BYTES, stream>>>(enc, b_proj, wpd, out);
}